// Round 7
// baseline (514.641 us; speedup 1.0000x reference)
//
#include <hip/hip_runtime.h>

// Swin-V2 shifted-window attention, fp32 in/out, MI355X gfx950.
// R11 = R8 EXACTLY (measured best: 287us dispatch, 674MB, occ 43%) with ONE
// change: LDS declared at true usage 32KB (was padded to 64KB to pin 2 blocks/CU).
// VGPR=64 + 32KB LDS -> 4 blocks/CU = 32 waves/CU (100% occupancy), doubling
// latency-hiding waves. R10's bundle (lane remap + b64 y-writes + load peeling)
// REVERTED: conflicts dropped 9.4->5.8M but FETCH/WRITE rose and dur 287->330us.
// Falsifier for this round: FETCH >350MB => L2 thrash at 4 blocks/CU (R5 mechanism).
// MFMA 16x16x32 bf16 layouts (HW-verified): A/B[row=lane&15][k=(lane>>4)*8+j],
// C/D[col=lane&15 (B.n)][row=(lane>>4)*4+reg (A.m)].
// Fragment-major storage of a [T x F] tile: addr(t,f) = ((f>>3)*64 + t)*8 + (f&7).

typedef __bf16 bf16_t;
typedef __attribute__((ext_vector_type(8))) __bf16 bf16x8;
typedef __attribute__((ext_vector_type(4))) float f32x4;

__device__ __forceinline__ f32x4 mfma16(bf16x8 a, bf16x8 b, f32x4 c) {
  return __builtin_amdgcn_mfma_f32_16x16x32_bf16(a, b, c, 0, 0, 0);
}

__device__ __forceinline__ bf16x8 cvt8(const float* f) {
  f32x4 a = *(const f32x4*)f;
  f32x4 b = *(const f32x4*)(f + 4);
  bf16x8 r;
  r[0] = (bf16_t)a.x; r[1] = (bf16_t)a.y; r[2] = (bf16_t)a.z; r[3] = (bf16_t)a.w;
  r[4] = (bf16_t)b.x; r[5] = (bf16_t)b.y; r[6] = (bf16_t)b.z; r[7] = (bf16_t)b.w;
  return r;
}

__device__ __forceinline__ uint32_t pack2(float a, float b) {
  union { bf16_t h[2]; uint32_t u; } t;
  t.h[0] = (bf16_t)a; t.h[1] = (bf16_t)b;
  return t.u;
}

__device__ __forceinline__ float clampv(float v) {
  return fminf(fmaxf(v, -1.0e4f), 1.0e4f);
}

// Build one A/B fragment from transposed per-lane C-layout data (R5-verified).
__device__ __forceinline__ bf16x8 quadshuf(uint32_t lo0, uint32_t hi0,
                                           uint32_t lo1, uint32_t hi1,
                                           int sA, int sB, bool miHi) {
  int a0 = __shfl((int)lo0, sA), a1 = __shfl((int)lo1, sA);
  int b0 = __shfl((int)hi0, sA), b1 = __shfl((int)hi1, sA);
  int c0 = __shfl((int)lo0, sB), c1 = __shfl((int)lo1, sB);
  int d0 = __shfl((int)hi0, sB), d1 = __shfl((int)hi1, sB);
  union { uint32_t w[4]; bf16x8 v; } f;
  f.w[0] = (uint32_t)(miHi ? a1 : a0);
  f.w[1] = (uint32_t)(miHi ? b1 : b0);
  f.w[2] = (uint32_t)(miHi ? c1 : c0);
  f.w[3] = (uint32_t)(miHi ? d1 : d0);
  return f.v;
}

// ---------------- merged prep: CPB-MLP bias table + fragment-major weights ----------
__global__ void prep_all(const float* __restrict__ Wq, const float* __restrict__ Wk,
                         const float* __restrict__ Wv, const float* __restrict__ Wo,
                         const float* __restrict__ w1, const float* __restrict__ b1,
                         const float* __restrict__ w2, bf16_t* __restrict__ wf,
                         float* __restrict__ tab, int doW) {
  if (blockIdx.x < 128) {
    if (!doW) return;
    int gid = blockIdx.x * 256 + threadIdx.x;  // 4 mats x 256 rows x 32 col-blocks
    int mat = gid >> 13, rem = gid & 8191;
    int row = rem >> 5, col = (rem & 31) << 3;
    const float* W = (mat == 0) ? Wq : (mat == 1) ? Wk : (mat == 2) ? Wv : Wo;
    bf16x8 v = cvt8(W + row * 256 + col);
    int rblk = row >> 4, kk = col >> 5, qd = (col >> 3) & 3, lr = row & 15;
    size_t dst = ((size_t)(((mat * 16 + rblk) * 8 + kk) * 64 + qd * 16 + lr)) * 8;
    *(bf16x8*)(wf + dst) = v;
    return;
  }
  if (threadIdx.x >= 64) return;
  int e = blockIdx.x - 128;  // 0..224
  int t = threadIdx.x;       // 0..63
  int a = e / 15, bcol = e % 15;
  float t0 = ((float)(a - 7) / 7.0f) * 8.0f;
  float t1 = ((float)(bcol - 7) / 7.0f) * 8.0f;
  float s0 = (t0 > 0.f) ? 1.f : ((t0 < 0.f) ? -1.f : 0.f);
  float s1 = (t1 > 0.f) ? 1.f : ((t1 < 0.f) ? -1.f : 0.f);
  t0 = s0 * log2f(fabsf(t0) + 1.f) * (1.0f / 3.0f);  // /log2(8)
  t1 = s1 * log2f(fabsf(t1) + 1.f) * (1.0f / 3.0f);
  float accv[8];
#pragma unroll
  for (int i = 0; i < 8; ++i) accv[i] = 0.f;
#pragma unroll
  for (int i = 0; i < 8; ++i) {
    int j = t + 64 * i;
    float hd = fmaxf(t0 * w1[2 * j] + t1 * w1[2 * j + 1] + b1[j], 0.f);
#pragma unroll
    for (int hh = 0; hh < 8; ++hh) accv[hh] += hd * w2[hh * 512 + j];
  }
#pragma unroll
  for (int hh = 0; hh < 8; ++hh) {
    float v = accv[hh];
    v += __shfl_xor(v, 1);  v += __shfl_xor(v, 2);  v += __shfl_xor(v, 4);
    v += __shfl_xor(v, 8);  v += __shfl_xor(v, 16); v += __shfl_xor(v, 32);
    accv[hh] = v;
  }
  if (t < 8) tab[e * 8 + t] = 16.f / (1.f + __expf(-accv[t]));
}

// ---------------- fused per-window attention ---------------------------------------
template <bool PREP>
__global__ void __launch_bounds__(512, 4) swin_fused(
    const float* __restrict__ x,
    const float* __restrict__ Wq, const float* __restrict__ bq,
    const float* __restrict__ Wk, const float* __restrict__ bk,
    const float* __restrict__ Wv, const float* __restrict__ bv,
    const float* __restrict__ Wo, const float* __restrict__ bo,
    const float* __restrict__ ls, const float* __restrict__ btab,
    const bf16_t* __restrict__ wf, float* __restrict__ out) {
  // 32 KB (true usage) => 4 blocks/CU (wave-slot-limited), 32 waves/CU.
  __shared__ __align__(16) bf16_t xsf[16384];
  const int tid = threadIdx.x;
  const int lane = tid & 63, wave = tid >> 6, quad = lane >> 4, l16 = lane & 15;
  const int win = blockIdx.x, bb = win >> 6, wh = (win >> 3) & 7, ww = win & 7;
  const f32x4 fz = {0.f, 0.f, 0.f, 0.f};
  const int sA = ((quad & 1) << 5) | l16;  // quadshuf source lanes
  const int sB = sA + 16;
  const bool miHi = (lane & 32) != 0;
  const int h = wave;  // one head per wave

  // ---- Phase 0: stage shifted x-window -> xsf (fragment-major bf16) ----
  {
    int t = tid >> 3, f8 = tid & 7;  // token 0..63, 32-channel group 0..7
    int gh = (wh * 8 + (t >> 3) + 4) & 63;
    int gw = (ww * 8 + (t & 7) + 4) & 63;
    const float* xp = x + (size_t)((bb * 64 + gh) * 64 + gw) * 256 + f8 * 32;
#pragma unroll
    for (int fc = 0; fc < 4; ++fc)
      *(bf16x8*)(xsf + (f8 * 4 + fc) * 512 + t * 8) = cvt8(xp + fc * 8);
  }
  __syncthreads();

  // shifted-window mask region ids (R5-verified).
  const bool lastr = (wh == 7), lastc = (ww == 7);
  int regm[4], regn[4];
#pragma unroll
  for (int b4 = 0; b4 < 4; ++b4) {
    regm[b4] = (lastr ? ((b4 * 2 + (quad >> 1)) < 4 ? 1 : 2) : 0) * 3 +
               (lastc ? ((quad & 1) ? 2 : 1) : 0);
    regn[b4] = (lastr ? ((b4 * 2 + (l16 >> 3)) < 4 ? 1 : 2) : 0) * 3 +
               (lastc ? (((l16 & 7) < 4) ? 1 : 2) : 0);
  }

  // ---- Phase A: projections. q,k SWAPPED (A=W -> out [dim][token]);
  //      v un-swapped (A=x -> out [token][dim]). ----
  f32x4 aq[2][4], ak[2][4], av[4][2];
#pragma unroll
  for (int mi = 0; mi < 2; ++mi)
#pragma unroll
    for (int nb = 0; nb < 4; ++nb) { aq[mi][nb] = fz; ak[mi][nb] = fz; }
#pragma unroll
  for (int mt = 0; mt < 4; ++mt) { av[mt][0] = fz; av[mt][1] = fz; }

#pragma unroll
  for (int kk = 0; kk < 8; ++kk) {
    bf16x8 af[4];
    const bf16_t* xb = xsf + ((kk * 4 + quad) * 64 + l16) * 8;
#pragma unroll
    for (int tb = 0; tb < 4; ++tb) af[tb] = *(const bf16x8*)(xb + tb * 128);
    bf16x8 wq_[2], wk_[2], wv_[2];
    if (PREP) {
      const bf16_t* wb = wf + (size_t)kk * 512 + (size_t)lane * 8;
#pragma unroll
      for (int mi = 0; mi < 2; ++mi) {
        wq_[mi] = *(const bf16x8*)(wb + (size_t)(h * 2 + mi) * 4096);
        wk_[mi] = *(const bf16x8*)(wb + (size_t)(16 + h * 2 + mi) * 4096);
        wv_[mi] = *(const bf16x8*)(wb + (size_t)(32 + h * 2 + mi) * 4096);
      }
    } else {
#pragma unroll
      for (int mi = 0; mi < 2; ++mi) {
        wq_[mi] = cvt8(Wq + (h * 32 + mi * 16 + l16) * 256 + kk * 32 + quad * 8);
        wk_[mi] = cvt8(Wk + (h * 32 + mi * 16 + l16) * 256 + kk * 32 + quad * 8);
        wv_[mi] = cvt8(Wv + (h * 32 + mi * 16 + l16) * 256 + kk * 32 + quad * 8);
      }
    }
#pragma unroll
    for (int mi = 0; mi < 2; ++mi)
#pragma unroll
      for (int tb = 0; tb < 4; ++tb) {
        aq[mi][tb] = mfma16(wq_[mi], af[tb], aq[mi][tb]);
        ak[mi][tb] = mfma16(wk_[mi], af[tb], ak[mi][tb]);
      }
#pragma unroll
    for (int mt = 0; mt < 4; ++mt)
#pragma unroll
      for (int nd = 0; nd < 2; ++nd)
        av[mt][nd] = mfma16(af[mt], wv_[nd], av[mt][nd]);
  }

  // ---- Phase B: bias + cosine-normalize (lane-local + 2 shfl), pack to bf16 ----
  float bqv[2][4], bkv[2][4];
#pragma unroll
  for (int mi = 0; mi < 2; ++mi)
#pragma unroll
    for (int r = 0; r < 4; ++r) {
      bqv[mi][r] = bq[h * 32 + mi * 16 + quad * 4 + r];
      bkv[mi][r] = bk[h * 32 + mi * 16 + quad * 4 + r];
    }
  const float bv0 = bv[h * 32 + l16], bv1 = bv[h * 32 + 16 + l16];

  uint32_t qlo[2][4], qhi[2][4], klo[2][4], khi[2][4];
#pragma unroll
  for (int nb = 0; nb < 4; ++nb) {
    float qv[2][4], kv[2][4];
    float sq = 0.f, sk = 0.f;
#pragma unroll
    for (int mi = 0; mi < 2; ++mi)
#pragma unroll
      for (int r = 0; r < 4; ++r) {
        float q0 = aq[mi][nb][r] + bqv[mi][r];
        float k0 = ak[mi][nb][r] + bkv[mi][r];
        qv[mi][r] = q0; kv[mi][r] = k0;
        sq += q0 * q0; sk += k0 * k0;
      }
    sq += __shfl_xor(sq, 16); sq += __shfl_xor(sq, 32);
    sk += __shfl_xor(sk, 16); sk += __shfl_xor(sk, 32);
    const float rq = 1.f / fmaxf(sqrtf(sq), 1e-12f);
    const float rk = 1.f / fmaxf(sqrtf(sk), 1e-12f);
#pragma unroll
    for (int mi = 0; mi < 2; ++mi) {
      qlo[mi][nb] = pack2(qv[mi][0] * rq, qv[mi][1] * rq);
      qhi[mi][nb] = pack2(qv[mi][2] * rq, qv[mi][3] * rq);
      klo[mi][nb] = pack2(kv[mi][0] * rk, kv[mi][1] * rk);
      khi[mi][nb] = pack2(kv[mi][2] * rk, kv[mi][3] * rk);
    }
  }
  uint32_t vlo[4][2], vhi[4][2];
#pragma unroll
  for (int mt = 0; mt < 4; ++mt)
#pragma unroll
    for (int nd = 0; nd < 2; ++nd) {
      const float bvb = nd ? bv1 : bv0;
      vlo[mt][nd] = pack2(av[mt][nd][0] + bvb, av[mt][nd][1] + bvb);
      vhi[mt][nd] = pack2(av[mt][nd][2] + bvb, av[mt][nd][3] + bvb);
    }

  // ---- Phase C: S^T = kn @ qn^T, fragments built in-register ----
  bf16x8 kfr[4], qfr[4];
#pragma unroll
  for (int tb = 0; tb < 4; ++tb)
    kfr[tb] = quadshuf(klo[0][tb], khi[0][tb], klo[1][tb], khi[1][tb], sA, sB, miHi);
#pragma unroll
  for (int tb = 0; tb < 4; ++tb)
    qfr[tb] = quadshuf(qlo[0][tb], qhi[0][tb], qlo[1][tb], qhi[1][tb], sA, sB, miHi);
  f32x4 s[4][4];  // s[KB][NB]: lane holds S[query NB*16+l16][key KB*16+quad*4+r]
#pragma unroll
  for (int KB = 0; KB < 4; ++KB)
#pragma unroll
    for (int NB = 0; NB < 4; ++NB) s[KB][NB] = mfma16(kfr[KB], qfr[NB], fz);

  const float scale = __expf(fminf(ls[h], 4.6051702f));  // exp(min(ls, ln 100))

  // ---- scale + CPB bias + shifted-window mask ----
#pragma unroll
  for (int KB = 0; KB < 4; ++KB) {
    const int mrow = KB * 2 + (quad >> 1);
    const int mcol0 = (quad & 1) * 4;
#pragma unroll
    for (int NB = 0; NB < 4; ++NB) {
      const int base = ((NB * 2 + (l16 >> 3)) - mrow + 7) * 15 +
                       ((l16 & 7) - mcol0 + 7);
      const bool msk = (regn[NB] != regm[KB]);
#pragma unroll
      for (int r = 0; r < 4; ++r) {
        float v = s[KB][NB][r] * scale + btab[(base - r) * 8 + h];
        if (msk) v -= 100.f;
        s[KB][NB][r] = v;
      }
    }
  }

  // ---- Phase D: softmax over keys (lane-local 16 + 2 shfl per query col) ----
  uint32_t plo[4][4], phi[4][4];
#pragma unroll
  for (int NB = 0; NB < 4; ++NB) {
    float mx = s[0][NB][0];
#pragma unroll
    for (int KB = 0; KB < 4; ++KB)
#pragma unroll
      for (int r = 0; r < 4; ++r) mx = fmaxf(mx, s[KB][NB][r]);
    mx = fmaxf(mx, __shfl_xor(mx, 16));
    mx = fmaxf(mx, __shfl_xor(mx, 32));
    float sum = 0.f;
#pragma unroll
    for (int KB = 0; KB < 4; ++KB)
#pragma unroll
      for (int r = 0; r < 4; ++r) {
        float p = __expf(s[KB][NB][r] - mx);
        s[KB][NB][r] = p;
        sum += p;
      }
    sum += __shfl_xor(sum, 16); sum += __shfl_xor(sum, 32);
    const float inv = 1.f / sum;
#pragma unroll
    for (int KB = 0; KB < 4; ++KB) {
      plo[KB][NB] = pack2(s[KB][NB][0] * inv, s[KB][NB][1] * inv);
      phi[KB][NB] = pack2(s[KB][NB][2] * inv, s[KB][NB][3] * inv);
    }
  }

  // ---- Phase E: O^T = V^T @ P (fragments in-register, 2 K-steps of 32 keys) ----
  f32x4 oh[2][4];  // [dim-block][query-block]
#pragma unroll
  for (int DB = 0; DB < 2; ++DB)
#pragma unroll
    for (int NB = 0; NB < 4; ++NB) oh[DB][NB] = fz;
#pragma unroll
  for (int st = 0; st < 2; ++st) {
    bf16x8 vfr[2], pfr[4];
#pragma unroll
    for (int DB = 0; DB < 2; ++DB)
      vfr[DB] = quadshuf(vlo[2 * st][DB], vhi[2 * st][DB],
                         vlo[2 * st + 1][DB], vhi[2 * st + 1][DB], sA, sB, miHi);
#pragma unroll
    for (int NB = 0; NB < 4; ++NB)
      pfr[NB] = quadshuf(plo[2 * st][NB], phi[2 * st][NB],
                         plo[2 * st + 1][NB], phi[2 * st + 1][NB], sA, sB, miHi);
#pragma unroll
    for (int DB = 0; DB < 2; ++DB)
#pragma unroll
      for (int NB = 0; NB < 4; ++NB)
        oh[DB][NB] = mfma16(vfr[DB], pfr[NB], oh[DB][NB]);
  }

  // all waves past their Phase-A xsf reads here; overlay y frags on xsf.
  __syncthreads();
  // write O^T into y frags: channel f = h*32 + DB*16 + quad*4 + r, token nb*16+l16
#pragma unroll
  for (int DB = 0; DB < 2; ++DB)
#pragma unroll
    for (int nb = 0; nb < 4; ++nb)
#pragma unroll
      for (int r = 0; r < 4; ++r)
        xsf[(h * 4 + DB * 2 + (quad >> 1)) * 512 + (nb * 16 + l16) * 8 +
            ((quad & 1) << 2) + r] = (bf16_t)oh[DB][nb][r];
  __syncthreads();

  // ---- Phase F: out = y @ Wo^T + bo (wave covers 32 out channels) ----
  f32x4 a2[4][2];
#pragma unroll
  for (int mi = 0; mi < 4; ++mi) { a2[mi][0] = fz; a2[mi][1] = fz; }

#pragma unroll
  for (int kk = 0; kk < 8; ++kk) {
    bf16x8 af[4];
    const bf16_t* yb = xsf + ((kk * 4 + quad) * 64 + l16) * 8;
#pragma unroll
    for (int mi = 0; mi < 4; ++mi) af[mi] = *(const bf16x8*)(yb + mi * 128);
#pragma unroll
    for (int ni = 0; ni < 2; ++ni) {
      bf16x8 bw;
      if (PREP)
        bw = *(const bf16x8*)(wf + (size_t)(((48 + wave * 2 + ni) * 8 + kk) * 64 + lane) * 8);
      else
        bw = cvt8(Wo + (wave * 32 + ni * 16 + l16) * 256 + kk * 32 + quad * 8);
#pragma unroll
      for (int mi = 0; mi < 4; ++mi) a2[mi][ni] = mfma16(af[mi], bw, a2[mi][ni]);
    }
  }

  const float bor0 = bo[wave * 32 + l16], bor1 = bo[wave * 32 + 16 + l16];
#pragma unroll
  for (int mi = 0; mi < 4; ++mi)
#pragma unroll
    for (int r = 0; r < 4; ++r) {
      int row = mi * 16 + quad * 4 + r;
      int gh = (wh * 8 + (row >> 3) + 4) & 63;
      int gw = (ww * 8 + (row & 7) + 4) & 63;
      float* op = out + (size_t)((bb * 64 + gh) * 64 + gw) * 256 + wave * 32 + l16;
      op[0]  = clampv(a2[mi][0][r] + bor0);
      op[16] = clampv(a2[mi][1][r] + bor1);
    }
}

extern "C" void kernel_launch(void* const* d_in, const int* in_sizes, int n_in,
                              void* d_out, int out_size, void* d_ws, size_t ws_size,
                              hipStream_t stream) {
  const float* x  = (const float*)d_in[0];
  const float* Wq = (const float*)d_in[1];
  const float* bq = (const float*)d_in[2];
  const float* Wk = (const float*)d_in[3];
  const float* bk = (const float*)d_in[4];
  const float* Wv = (const float*)d_in[5];
  const float* bv = (const float*)d_in[6];
  const float* Wo = (const float*)d_in[7];
  const float* bo = (const float*)d_in[8];
  const float* ls = (const float*)d_in[9];
  const float* w1 = (const float*)d_in[10];
  const float* b1 = (const float*)d_in[11];
  const float* w2 = (const float*)d_in[12];

  float* tab = (float*)d_ws;                           // 1800 floats (7.2 KB)
  bf16_t* wfrag = (bf16_t*)((char*)d_ws + 7680);       // 512 KB fragment-major weights
  const bool prep = ws_size >= (size_t)(7680 + 524288);  // constant across calls

  hipLaunchKernelGGL(prep_all, dim3(353), dim3(256), 0, stream,
                     Wq, Wk, Wv, Wo, w1, b1, w2, wfrag, tab, prep ? 1 : 0);
  if (prep) {
    hipLaunchKernelGGL((swin_fused<true>), dim3(2048), dim3(512), 0, stream,
                       x, Wq, bq, Wk, bk, Wv, bv, Wo, bo, ls, tab, wfrag, (float*)d_out);
  } else {
    hipLaunchKernelGGL((swin_fused<false>), dim3(2048), dim3(512), 0, stream,
                       x, Wq, bq, Wk, bk, Wv, bv, Wo, bo, ls, tab, wfrag, (float*)d_out);
  }
}

// Round 8
// 498.428 us; speedup vs baseline: 1.0325x; 1.0325x over previous
//
#include <hip/hip_runtime.h>

// Swin-V2 shifted-window attention, fp32 in/out, MI355X gfx950.
// R12 = R8 EXACTLY (measured best: 287us dispatch, 2 blocks/CU pinned) with ONE
// coherent change: remove all data-independent loads from the serial chain.
//  - CPB bias table: 64 per-lane scattered GLOBAL gathers in the mask phase
//    (unhideable: softmax depends on them) -> per-wave LDS stage at kernel entry,
//    REVERSED layout (tabs[h][224-idx]) so r-loop reads are contiguous.
//  - bq/bk/bv/bo/ls loads + scale hoisted to kernel entry (latency hides under
//    Phase-0 x staging).
//  - LDS padded (xsf[25920] + tabs) to 58.8KB -> still exactly 2 blocks/CU
//    (R11 falsified >=3 blocks/CU: FETCH 203->310MB, WRITE 455->703MB, +70us).
// MFMA 16x16x32 bf16 layouts (HW-verified): A/B[row=lane&15][k=(lane>>4)*8+j],
// C/D[col=lane&15 (B.n)][row=(lane>>4)*4+reg (A.m)].
// Fragment-major storage of a [T x F] tile: addr(t,f) = ((f>>3)*64 + t)*8 + (f&7).

typedef __bf16 bf16_t;
typedef __attribute__((ext_vector_type(8))) __bf16 bf16x8;
typedef __attribute__((ext_vector_type(4))) float f32x4;

__device__ __forceinline__ f32x4 mfma16(bf16x8 a, bf16x8 b, f32x4 c) {
  return __builtin_amdgcn_mfma_f32_16x16x32_bf16(a, b, c, 0, 0, 0);
}

__device__ __forceinline__ bf16x8 cvt8(const float* f) {
  f32x4 a = *(const f32x4*)f;
  f32x4 b = *(const f32x4*)(f + 4);
  bf16x8 r;
  r[0] = (bf16_t)a.x; r[1] = (bf16_t)a.y; r[2] = (bf16_t)a.z; r[3] = (bf16_t)a.w;
  r[4] = (bf16_t)b.x; r[5] = (bf16_t)b.y; r[6] = (bf16_t)b.z; r[7] = (bf16_t)b.w;
  return r;
}

__device__ __forceinline__ uint32_t pack2(float a, float b) {
  union { bf16_t h[2]; uint32_t u; } t;
  t.h[0] = (bf16_t)a; t.h[1] = (bf16_t)b;
  return t.u;
}

__device__ __forceinline__ float clampv(float v) {
  return fminf(fmaxf(v, -1.0e4f), 1.0e4f);
}

// Build one A/B fragment from transposed per-lane C-layout data (R5-verified).
__device__ __forceinline__ bf16x8 quadshuf(uint32_t lo0, uint32_t hi0,
                                           uint32_t lo1, uint32_t hi1,
                                           int sA, int sB, bool miHi) {
  int a0 = __shfl((int)lo0, sA), a1 = __shfl((int)lo1, sA);
  int b0 = __shfl((int)hi0, sA), b1 = __shfl((int)hi1, sA);
  int c0 = __shfl((int)lo0, sB), c1 = __shfl((int)lo1, sB);
  int d0 = __shfl((int)hi0, sB), d1 = __shfl((int)hi1, sB);
  union { uint32_t w[4]; bf16x8 v; } f;
  f.w[0] = (uint32_t)(miHi ? a1 : a0);
  f.w[1] = (uint32_t)(miHi ? b1 : b0);
  f.w[2] = (uint32_t)(miHi ? c1 : c0);
  f.w[3] = (uint32_t)(miHi ? d1 : d0);
  return f.v;
}

// ---------------- merged prep: CPB-MLP bias table + fragment-major weights ----------
__global__ void prep_all(const float* __restrict__ Wq, const float* __restrict__ Wk,
                         const float* __restrict__ Wv, const float* __restrict__ Wo,
                         const float* __restrict__ w1, const float* __restrict__ b1,
                         const float* __restrict__ w2, bf16_t* __restrict__ wf,
                         float* __restrict__ tab, int doW) {
  if (blockIdx.x < 128) {
    if (!doW) return;
    int gid = blockIdx.x * 256 + threadIdx.x;  // 4 mats x 256 rows x 32 col-blocks
    int mat = gid >> 13, rem = gid & 8191;
    int row = rem >> 5, col = (rem & 31) << 3;
    const float* W = (mat == 0) ? Wq : (mat == 1) ? Wk : (mat == 2) ? Wv : Wo;
    bf16x8 v = cvt8(W + row * 256 + col);
    int rblk = row >> 4, kk = col >> 5, qd = (col >> 3) & 3, lr = row & 15;
    size_t dst = ((size_t)(((mat * 16 + rblk) * 8 + kk) * 64 + qd * 16 + lr)) * 8;
    *(bf16x8*)(wf + dst) = v;
    return;
  }
  if (threadIdx.x >= 64) return;
  int e = blockIdx.x - 128;  // 0..224
  int t = threadIdx.x;       // 0..63
  int a = e / 15, bcol = e % 15;
  float t0 = ((float)(a - 7) / 7.0f) * 8.0f;
  float t1 = ((float)(bcol - 7) / 7.0f) * 8.0f;
  float s0 = (t0 > 0.f) ? 1.f : ((t0 < 0.f) ? -1.f : 0.f);
  float s1 = (t1 > 0.f) ? 1.f : ((t1 < 0.f) ? -1.f : 0.f);
  t0 = s0 * log2f(fabsf(t0) + 1.f) * (1.0f / 3.0f);  // /log2(8)
  t1 = s1 * log2f(fabsf(t1) + 1.f) * (1.0f / 3.0f);
  float accv[8];
#pragma unroll
  for (int i = 0; i < 8; ++i) accv[i] = 0.f;
#pragma unroll
  for (int i = 0; i < 8; ++i) {
    int j = t + 64 * i;
    float hd = fmaxf(t0 * w1[2 * j] + t1 * w1[2 * j + 1] + b1[j], 0.f);
#pragma unroll
    for (int hh = 0; hh < 8; ++hh) accv[hh] += hd * w2[hh * 512 + j];
  }
#pragma unroll
  for (int hh = 0; hh < 8; ++hh) {
    float v = accv[hh];
    v += __shfl_xor(v, 1);  v += __shfl_xor(v, 2);  v += __shfl_xor(v, 4);
    v += __shfl_xor(v, 8);  v += __shfl_xor(v, 16); v += __shfl_xor(v, 32);
    accv[hh] = v;
  }
  if (t < 8) tab[e * 8 + t] = 16.f / (1.f + __expf(-accv[t]));
}

// ---------------- fused per-window attention ---------------------------------------
template <bool PREP>
__global__ void __launch_bounds__(512, 4) swin_fused(
    const float* __restrict__ x,
    const float* __restrict__ Wq, const float* __restrict__ bq,
    const float* __restrict__ Wk, const float* __restrict__ bk,
    const float* __restrict__ Wv, const float* __restrict__ bv,
    const float* __restrict__ Wo, const float* __restrict__ bo,
    const float* __restrict__ ls, const float* __restrict__ btab,
    const bf16_t* __restrict__ wf, float* __restrict__ out) {
  // xsf: first 16384 elems used (32KB); oversized to 51.8KB so total LDS
  // (+ tabs 7.4KB) = 58.8KB -> exactly 2 blocks/CU (3x would exceed 160KB).
  __shared__ __align__(16) bf16_t xsf[25920];
  __shared__ float tabs[8][232];  // per-head CPB bias, reversed: tabs[h][224-idx]
  const int tid = threadIdx.x;
  const int lane = tid & 63, wave = tid >> 6, quad = lane >> 4, l16 = lane & 15;
  const int win = blockIdx.x, bb = win >> 6, wh = (win >> 3) & 7, ww = win & 7;
  const f32x4 fz = {0.f, 0.f, 0.f, 0.f};
  const int sA = ((quad & 1) << 5) | l16;  // quadshuf source lanes
  const int sB = sA + 16;
  const bool miHi = (lane & 32) != 0;
  const int h = wave;  // one head per wave

  // ---- Entry: all data-independent loads issued up front ----
  // (1) per-wave head-slice of CPB table -> LDS, reversed for contiguous r-reads
#pragma unroll
  for (int i = 0; i < 4; ++i) {
    int idx = lane + 64 * i;
    if (idx < 225) tabs[wave][224 - idx] = btab[idx * 8 + wave];
  }
  // (2) biases + logit scale (lane-geometry-only, held in regs)
  const float scale = __expf(fminf(ls[h], 4.6051702f));  // exp(min(ls, ln 100))
  float bqv[2][4], bkv[2][4];
#pragma unroll
  for (int mi = 0; mi < 2; ++mi)
#pragma unroll
    for (int r = 0; r < 4; ++r) {
      bqv[mi][r] = bq[h * 32 + mi * 16 + quad * 4 + r];
      bkv[mi][r] = bk[h * 32 + mi * 16 + quad * 4 + r];
    }
  const float bv0 = bv[h * 32 + l16], bv1 = bv[h * 32 + 16 + l16];
  const float bor0 = bo[wave * 32 + l16], bor1 = bo[wave * 32 + 16 + l16];

  // ---- Phase 0: stage shifted x-window -> xsf (fragment-major bf16) ----
  {
    int t = tid >> 3, f8 = tid & 7;  // token 0..63, 32-channel group 0..7
    int gh = (wh * 8 + (t >> 3) + 4) & 63;
    int gw = (ww * 8 + (t & 7) + 4) & 63;
    const float* xp = x + (size_t)((bb * 64 + gh) * 64 + gw) * 256 + f8 * 32;
#pragma unroll
    for (int fc = 0; fc < 4; ++fc)
      *(bf16x8*)(xsf + (f8 * 4 + fc) * 512 + t * 8) = cvt8(xp + fc * 8);
  }
  __syncthreads();

  // shifted-window mask region ids (R5-verified).
  const bool lastr = (wh == 7), lastc = (ww == 7);
  int regm[4], regn[4];
#pragma unroll
  for (int b4 = 0; b4 < 4; ++b4) {
    regm[b4] = (lastr ? ((b4 * 2 + (quad >> 1)) < 4 ? 1 : 2) : 0) * 3 +
               (lastc ? ((quad & 1) ? 2 : 1) : 0);
    regn[b4] = (lastr ? ((b4 * 2 + (l16 >> 3)) < 4 ? 1 : 2) : 0) * 3 +
               (lastc ? (((l16 & 7) < 4) ? 1 : 2) : 0);
  }

  // ---- Phase A: projections. q,k SWAPPED (A=W -> out [dim][token]);
  //      v un-swapped (A=x -> out [token][dim]). ----
  f32x4 aq[2][4], ak[2][4], av[4][2];
#pragma unroll
  for (int mi = 0; mi < 2; ++mi)
#pragma unroll
    for (int nb = 0; nb < 4; ++nb) { aq[mi][nb] = fz; ak[mi][nb] = fz; }
#pragma unroll
  for (int mt = 0; mt < 4; ++mt) { av[mt][0] = fz; av[mt][1] = fz; }

#pragma unroll
  for (int kk = 0; kk < 8; ++kk) {
    bf16x8 af[4];
    const bf16_t* xb = xsf + ((kk * 4 + quad) * 64 + l16) * 8;
#pragma unroll
    for (int tb = 0; tb < 4; ++tb) af[tb] = *(const bf16x8*)(xb + tb * 128);
    bf16x8 wq_[2], wk_[2], wv_[2];
    if (PREP) {
      const bf16_t* wb = wf + (size_t)kk * 512 + (size_t)lane * 8;
#pragma unroll
      for (int mi = 0; mi < 2; ++mi) {
        wq_[mi] = *(const bf16x8*)(wb + (size_t)(h * 2 + mi) * 4096);
        wk_[mi] = *(const bf16x8*)(wb + (size_t)(16 + h * 2 + mi) * 4096);
        wv_[mi] = *(const bf16x8*)(wb + (size_t)(32 + h * 2 + mi) * 4096);
      }
    } else {
#pragma unroll
      for (int mi = 0; mi < 2; ++mi) {
        wq_[mi] = cvt8(Wq + (h * 32 + mi * 16 + l16) * 256 + kk * 32 + quad * 8);
        wk_[mi] = cvt8(Wk + (h * 32 + mi * 16 + l16) * 256 + kk * 32 + quad * 8);
        wv_[mi] = cvt8(Wv + (h * 32 + mi * 16 + l16) * 256 + kk * 32 + quad * 8);
      }
    }
#pragma unroll
    for (int mi = 0; mi < 2; ++mi)
#pragma unroll
      for (int tb = 0; tb < 4; ++tb) {
        aq[mi][tb] = mfma16(wq_[mi], af[tb], aq[mi][tb]);
        ak[mi][tb] = mfma16(wk_[mi], af[tb], ak[mi][tb]);
      }
#pragma unroll
    for (int mt = 0; mt < 4; ++mt)
#pragma unroll
      for (int nd = 0; nd < 2; ++nd)
        av[mt][nd] = mfma16(af[mt], wv_[nd], av[mt][nd]);
  }

  // ---- Phase B: bias + cosine-normalize (lane-local + 2 shfl), pack to bf16 ----
  uint32_t qlo[2][4], qhi[2][4], klo[2][4], khi[2][4];
#pragma unroll
  for (int nb = 0; nb < 4; ++nb) {
    float qv[2][4], kv[2][4];
    float sq = 0.f, sk = 0.f;
#pragma unroll
    for (int mi = 0; mi < 2; ++mi)
#pragma unroll
      for (int r = 0; r < 4; ++r) {
        float q0 = aq[mi][nb][r] + bqv[mi][r];
        float k0 = ak[mi][nb][r] + bkv[mi][r];
        qv[mi][r] = q0; kv[mi][r] = k0;
        sq += q0 * q0; sk += k0 * k0;
      }
    sq += __shfl_xor(sq, 16); sq += __shfl_xor(sq, 32);
    sk += __shfl_xor(sk, 16); sk += __shfl_xor(sk, 32);
    const float rq = 1.f / fmaxf(sqrtf(sq), 1e-12f);
    const float rk = 1.f / fmaxf(sqrtf(sk), 1e-12f);
#pragma unroll
    for (int mi = 0; mi < 2; ++mi) {
      qlo[mi][nb] = pack2(qv[mi][0] * rq, qv[mi][1] * rq);
      qhi[mi][nb] = pack2(qv[mi][2] * rq, qv[mi][3] * rq);
      klo[mi][nb] = pack2(kv[mi][0] * rk, kv[mi][1] * rk);
      khi[mi][nb] = pack2(kv[mi][2] * rk, kv[mi][3] * rk);
    }
  }
  uint32_t vlo[4][2], vhi[4][2];
#pragma unroll
  for (int mt = 0; mt < 4; ++mt)
#pragma unroll
    for (int nd = 0; nd < 2; ++nd) {
      const float bvb = nd ? bv1 : bv0;
      vlo[mt][nd] = pack2(av[mt][nd][0] + bvb, av[mt][nd][1] + bvb);
      vhi[mt][nd] = pack2(av[mt][nd][2] + bvb, av[mt][nd][3] + bvb);
    }

  // ---- Phase C: S^T = kn @ qn^T, fragments built in-register ----
  bf16x8 kfr[4], qfr[4];
#pragma unroll
  for (int tb = 0; tb < 4; ++tb)
    kfr[tb] = quadshuf(klo[0][tb], khi[0][tb], klo[1][tb], khi[1][tb], sA, sB, miHi);
#pragma unroll
  for (int tb = 0; tb < 4; ++tb)
    qfr[tb] = quadshuf(qlo[0][tb], qhi[0][tb], qlo[1][tb], qhi[1][tb], sA, sB, miHi);
  f32x4 s[4][4];  // s[KB][NB]: lane holds S[query NB*16+l16][key KB*16+quad*4+r]
#pragma unroll
  for (int KB = 0; KB < 4; ++KB)
#pragma unroll
    for (int NB = 0; NB < 4; ++NB) s[KB][NB] = mfma16(kfr[KB], qfr[NB], fz);

  // ---- scale + CPB bias (LDS, contiguous in r) + shifted-window mask ----
  const float* th = tabs[wave];
#pragma unroll
  for (int KB = 0; KB < 4; ++KB) {
    const int mrow = KB * 2 + (quad >> 1);
    const int mcol0 = (quad & 1) * 4;
#pragma unroll
    for (int NB = 0; NB < 4; ++NB) {
      const int base = ((NB * 2 + (l16 >> 3)) - mrow + 7) * 15 +
                       ((l16 & 7) - mcol0 + 7);
      const int rb = 224 - base;
      const bool msk = (regn[NB] != regm[KB]);
#pragma unroll
      for (int r = 0; r < 4; ++r) {
        float v = s[KB][NB][r] * scale + th[rb + r];
        if (msk) v -= 100.f;
        s[KB][NB][r] = v;
      }
    }
  }

  // ---- Phase D: softmax over keys (lane-local 16 + 2 shfl per query col) ----
  uint32_t plo[4][4], phi[4][4];
#pragma unroll
  for (int NB = 0; NB < 4; ++NB) {
    float mx = s[0][NB][0];
#pragma unroll
    for (int KB = 0; KB < 4; ++KB)
#pragma unroll
      for (int r = 0; r < 4; ++r) mx = fmaxf(mx, s[KB][NB][r]);
    mx = fmaxf(mx, __shfl_xor(mx, 16));
    mx = fmaxf(mx, __shfl_xor(mx, 32));
    float sum = 0.f;
#pragma unroll
    for (int KB = 0; KB < 4; ++KB)
#pragma unroll
      for (int r = 0; r < 4; ++r) {
        float p = __expf(s[KB][NB][r] - mx);
        s[KB][NB][r] = p;
        sum += p;
      }
    sum += __shfl_xor(sum, 16); sum += __shfl_xor(sum, 32);
    const float inv = 1.f / sum;
#pragma unroll
    for (int KB = 0; KB < 4; ++KB) {
      plo[KB][NB] = pack2(s[KB][NB][0] * inv, s[KB][NB][1] * inv);
      phi[KB][NB] = pack2(s[KB][NB][2] * inv, s[KB][NB][3] * inv);
    }
  }

  // ---- Phase E: O^T = V^T @ P (fragments in-register, 2 K-steps of 32 keys) ----
  f32x4 oh[2][4];  // [dim-block][query-block]
#pragma unroll
  for (int DB = 0; DB < 2; ++DB)
#pragma unroll
    for (int NB = 0; NB < 4; ++NB) oh[DB][NB] = fz;
#pragma unroll
  for (int st = 0; st < 2; ++st) {
    bf16x8 vfr[2], pfr[4];
#pragma unroll
    for (int DB = 0; DB < 2; ++DB)
      vfr[DB] = quadshuf(vlo[2 * st][DB], vhi[2 * st][DB],
                         vlo[2 * st + 1][DB], vhi[2 * st + 1][DB], sA, sB, miHi);
#pragma unroll
    for (int NB = 0; NB < 4; ++NB)
      pfr[NB] = quadshuf(plo[2 * st][NB], phi[2 * st][NB],
                         plo[2 * st + 1][NB], phi[2 * st + 1][NB], sA, sB, miHi);
#pragma unroll
    for (int DB = 0; DB < 2; ++DB)
#pragma unroll
      for (int NB = 0; NB < 4; ++NB)
        oh[DB][NB] = mfma16(vfr[DB], pfr[NB], oh[DB][NB]);
  }

  // all waves past their Phase-A xsf reads here; overlay y frags on xsf.
  __syncthreads();
  // write O^T into y frags: channel f = h*32 + DB*16 + quad*4 + r, token nb*16+l16
#pragma unroll
  for (int DB = 0; DB < 2; ++DB)
#pragma unroll
    for (int nb = 0; nb < 4; ++nb)
#pragma unroll
      for (int r = 0; r < 4; ++r)
        xsf[(h * 4 + DB * 2 + (quad >> 1)) * 512 + (nb * 16 + l16) * 8 +
            ((quad & 1) << 2) + r] = (bf16_t)oh[DB][nb][r];
  __syncthreads();

  // ---- Phase F: out = y @ Wo^T + bo (wave covers 32 out channels) ----
  f32x4 a2[4][2];
#pragma unroll
  for (int mi = 0; mi < 4; ++mi) { a2[mi][0] = fz; a2[mi][1] = fz; }

#pragma unroll
  for (int kk = 0; kk < 8; ++kk) {
    bf16x8 af[4];
    const bf16_t* yb = xsf + ((kk * 4 + quad) * 64 + l16) * 8;
#pragma unroll
    for (int mi = 0; mi < 4; ++mi) af[mi] = *(const bf16x8*)(yb + mi * 128);
#pragma unroll
    for (int ni = 0; ni < 2; ++ni) {
      bf16x8 bw;
      if (PREP)
        bw = *(const bf16x8*)(wf + (size_t)(((48 + wave * 2 + ni) * 8 + kk) * 64 + lane) * 8);
      else
        bw = cvt8(Wo + (wave * 32 + ni * 16 + l16) * 256 + kk * 32 + quad * 8);
#pragma unroll
      for (int mi = 0; mi < 4; ++mi) a2[mi][ni] = mfma16(af[mi], bw, a2[mi][ni]);
    }
  }

#pragma unroll
  for (int mi = 0; mi < 4; ++mi)
#pragma unroll
    for (int r = 0; r < 4; ++r) {
      int row = mi * 16 + quad * 4 + r;
      int gh = (wh * 8 + (row >> 3) + 4) & 63;
      int gw = (ww * 8 + (row & 7) + 4) & 63;
      float* op = out + (size_t)((bb * 64 + gh) * 64 + gw) * 256 + wave * 32 + l16;
      op[0]  = clampv(a2[mi][0][r] + bor0);
      op[16] = clampv(a2[mi][1][r] + bor1);
    }
}

extern "C" void kernel_launch(void* const* d_in, const int* in_sizes, int n_in,
                              void* d_out, int out_size, void* d_ws, size_t ws_size,
                              hipStream_t stream) {
  const float* x  = (const float*)d_in[0];
  const float* Wq = (const float*)d_in[1];
  const float* bq = (const float*)d_in[2];
  const float* Wk = (const float*)d_in[3];
  const float* bk = (const float*)d_in[4];
  const float* Wv = (const float*)d_in[5];
  const float* bv = (const float*)d_in[6];
  const float* Wo = (const float*)d_in[7];
  const float* bo = (const float*)d_in[8];
  const float* ls = (const float*)d_in[9];
  const float* w1 = (const float*)d_in[10];
  const float* b1 = (const float*)d_in[11];
  const float* w2 = (const float*)d_in[12];

  float* tab = (float*)d_ws;                           // 1800 floats (7.2 KB)
  bf16_t* wfrag = (bf16_t*)((char*)d_ws + 7680);       // 512 KB fragment-major weights
  const bool prep = ws_size >= (size_t)(7680 + 524288);  // constant across calls

  hipLaunchKernelGGL(prep_all, dim3(353), dim3(256), 0, stream,
                     Wq, Wk, Wv, Wo, w1, b1, w2, wfrag, tab, prep ? 1 : 0);
  if (prep) {
    hipLaunchKernelGGL((swin_fused<true>), dim3(2048), dim3(512), 0, stream,
                       x, Wq, bq, Wk, bk, Wv, bv, Wo, bo, ls, tab, wfrag, (float*)d_out);
  } else {
    hipLaunchKernelGGL((swin_fused<false>), dim3(2048), dim3(512), 0, stream,
                       x, Wq, bq, Wk, bk, Wv, bv, Wo, bo, ls, tab, wfrag, (float*)d_out);
  }
}

// Round 9
// 451.604 us; speedup vs baseline: 1.1396x; 1.1037x over previous
//
#include <hip/hip_runtime.h>

// Swin-V2 shifted-window attention, fp32 in/out, MI355X gfx950.
// R13 = R8 EXACTLY (measured best: 287us dispatch; R11/R12 regressions reverted)
// with ONE change: manual 1-deep software pipeline of weight loads in Phases A/F.
// R8's VGPR_Count=64 shows the compiler register-minimized and serialises
// load->wait->MFMA per kk step (16 exposed L2 round-trips per block).
// Double-buffered weight regs (+~56 VGPR, budget 128 per launch_bounds(512,4))
// express the overlap; addresses/traffic identical, only issue order changes.
// Traffic counters (FETCH/WRITE) are NOT steering targets anymore: R9/R12 showed
// they respond to eviction timing, not store shape. Steer by dur_us + pipes.
// MFMA 16x16x32 bf16 layouts (HW-verified): A/B[row=lane&15][k=(lane>>4)*8+j],
// C/D[col=lane&15 (B.n)][row=(lane>>4)*4+reg (A.m)].
// Fragment-major storage of a [T x F] tile: addr(t,f) = ((f>>3)*64 + t)*8 + (f&7).

typedef __bf16 bf16_t;
typedef __attribute__((ext_vector_type(8))) __bf16 bf16x8;
typedef __attribute__((ext_vector_type(4))) float f32x4;

__device__ __forceinline__ f32x4 mfma16(bf16x8 a, bf16x8 b, f32x4 c) {
  return __builtin_amdgcn_mfma_f32_16x16x32_bf16(a, b, c, 0, 0, 0);
}

__device__ __forceinline__ bf16x8 cvt8(const float* f) {
  f32x4 a = *(const f32x4*)f;
  f32x4 b = *(const f32x4*)(f + 4);
  bf16x8 r;
  r[0] = (bf16_t)a.x; r[1] = (bf16_t)a.y; r[2] = (bf16_t)a.z; r[3] = (bf16_t)a.w;
  r[4] = (bf16_t)b.x; r[5] = (bf16_t)b.y; r[6] = (bf16_t)b.z; r[7] = (bf16_t)b.w;
  return r;
}

__device__ __forceinline__ uint32_t pack2(float a, float b) {
  union { bf16_t h[2]; uint32_t u; } t;
  t.h[0] = (bf16_t)a; t.h[1] = (bf16_t)b;
  return t.u;
}

__device__ __forceinline__ float clampv(float v) {
  return fminf(fmaxf(v, -1.0e4f), 1.0e4f);
}

// Build one A/B fragment from transposed per-lane C-layout data (R5-verified).
__device__ __forceinline__ bf16x8 quadshuf(uint32_t lo0, uint32_t hi0,
                                           uint32_t lo1, uint32_t hi1,
                                           int sA, int sB, bool miHi) {
  int a0 = __shfl((int)lo0, sA), a1 = __shfl((int)lo1, sA);
  int b0 = __shfl((int)hi0, sA), b1 = __shfl((int)hi1, sA);
  int c0 = __shfl((int)lo0, sB), c1 = __shfl((int)lo1, sB);
  int d0 = __shfl((int)hi0, sB), d1 = __shfl((int)hi1, sB);
  union { uint32_t w[4]; bf16x8 v; } f;
  f.w[0] = (uint32_t)(miHi ? a1 : a0);
  f.w[1] = (uint32_t)(miHi ? b1 : b0);
  f.w[2] = (uint32_t)(miHi ? c1 : c0);
  f.w[3] = (uint32_t)(miHi ? d1 : d0);
  return f.v;
}

// ---------------- merged prep: CPB-MLP bias table + fragment-major weights ----------
__global__ void prep_all(const float* __restrict__ Wq, const float* __restrict__ Wk,
                         const float* __restrict__ Wv, const float* __restrict__ Wo,
                         const float* __restrict__ w1, const float* __restrict__ b1,
                         const float* __restrict__ w2, bf16_t* __restrict__ wf,
                         float* __restrict__ tab, int doW) {
  if (blockIdx.x < 128) {
    if (!doW) return;
    int gid = blockIdx.x * 256 + threadIdx.x;  // 4 mats x 256 rows x 32 col-blocks
    int mat = gid >> 13, rem = gid & 8191;
    int row = rem >> 5, col = (rem & 31) << 3;
    const float* W = (mat == 0) ? Wq : (mat == 1) ? Wk : (mat == 2) ? Wv : Wo;
    bf16x8 v = cvt8(W + row * 256 + col);
    int rblk = row >> 4, kk = col >> 5, qd = (col >> 3) & 3, lr = row & 15;
    size_t dst = ((size_t)(((mat * 16 + rblk) * 8 + kk) * 64 + qd * 16 + lr)) * 8;
    *(bf16x8*)(wf + dst) = v;
    return;
  }
  if (threadIdx.x >= 64) return;
  int e = blockIdx.x - 128;  // 0..224
  int t = threadIdx.x;       // 0..63
  int a = e / 15, bcol = e % 15;
  float t0 = ((float)(a - 7) / 7.0f) * 8.0f;
  float t1 = ((float)(bcol - 7) / 7.0f) * 8.0f;
  float s0 = (t0 > 0.f) ? 1.f : ((t0 < 0.f) ? -1.f : 0.f);
  float s1 = (t1 > 0.f) ? 1.f : ((t1 < 0.f) ? -1.f : 0.f);
  t0 = s0 * log2f(fabsf(t0) + 1.f) * (1.0f / 3.0f);  // /log2(8)
  t1 = s1 * log2f(fabsf(t1) + 1.f) * (1.0f / 3.0f);
  float accv[8];
#pragma unroll
  for (int i = 0; i < 8; ++i) accv[i] = 0.f;
#pragma unroll
  for (int i = 0; i < 8; ++i) {
    int j = t + 64 * i;
    float hd = fmaxf(t0 * w1[2 * j] + t1 * w1[2 * j + 1] + b1[j], 0.f);
#pragma unroll
    for (int hh = 0; hh < 8; ++hh) accv[hh] += hd * w2[hh * 512 + j];
  }
#pragma unroll
  for (int hh = 0; hh < 8; ++hh) {
    float v = accv[hh];
    v += __shfl_xor(v, 1);  v += __shfl_xor(v, 2);  v += __shfl_xor(v, 4);
    v += __shfl_xor(v, 8);  v += __shfl_xor(v, 16); v += __shfl_xor(v, 32);
    accv[hh] = v;
  }
  if (t < 8) tab[e * 8 + t] = 16.f / (1.f + __expf(-accv[t]));
}

// ---------------- fused per-window attention ---------------------------------------
template <bool PREP>
__global__ void __launch_bounds__(512, 4) swin_fused(
    const float* __restrict__ x,
    const float* __restrict__ Wq, const float* __restrict__ bq,
    const float* __restrict__ Wk, const float* __restrict__ bk,
    const float* __restrict__ Wv, const float* __restrict__ bv,
    const float* __restrict__ Wo, const float* __restrict__ bo,
    const float* __restrict__ ls, const float* __restrict__ btab,
    const bf16_t* __restrict__ wf, float* __restrict__ out) {
  // 64 KB declared (32 KB used + pad) => exactly 2 blocks/CU (R11 falsified more).
  __shared__ __align__(16) bf16_t xsf[32768];
  const int tid = threadIdx.x;
  const int lane = tid & 63, wave = tid >> 6, quad = lane >> 4, l16 = lane & 15;
  const int win = blockIdx.x, bb = win >> 6, wh = (win >> 3) & 7, ww = win & 7;
  const f32x4 fz = {0.f, 0.f, 0.f, 0.f};
  const int sA = ((quad & 1) << 5) | l16;  // quadshuf source lanes
  const int sB = sA + 16;
  const bool miHi = (lane & 32) != 0;
  const int h = wave;  // one head per wave

  // ---- Phase 0: stage shifted x-window -> xsf (fragment-major bf16) ----
  {
    int t = tid >> 3, f8 = tid & 7;  // token 0..63, 32-channel group 0..7
    int gh = (wh * 8 + (t >> 3) + 4) & 63;
    int gw = (ww * 8 + (t & 7) + 4) & 63;
    const float* xp = x + (size_t)((bb * 64 + gh) * 64 + gw) * 256 + f8 * 32;
#pragma unroll
    for (int fc = 0; fc < 4; ++fc)
      *(bf16x8*)(xsf + (f8 * 4 + fc) * 512 + t * 8) = cvt8(xp + fc * 8);
  }
  __syncthreads();

  // shifted-window mask region ids (R5-verified).
  const bool lastr = (wh == 7), lastc = (ww == 7);
  int regm[4], regn[4];
#pragma unroll
  for (int b4 = 0; b4 < 4; ++b4) {
    regm[b4] = (lastr ? ((b4 * 2 + (quad >> 1)) < 4 ? 1 : 2) : 0) * 3 +
               (lastc ? ((quad & 1) ? 2 : 1) : 0);
    regn[b4] = (lastr ? ((b4 * 2 + (l16 >> 3)) < 4 ? 1 : 2) : 0) * 3 +
               (lastc ? (((l16 & 7) < 4) ? 1 : 2) : 0);
  }

  // ---- Phase A: projections, software-pipelined weight loads (1-deep).
  //      q,k SWAPPED (A=W -> out [dim][token]); v un-swapped. ----
  f32x4 aq[2][4], ak[2][4], av[4][2];
#pragma unroll
  for (int mi = 0; mi < 2; ++mi)
#pragma unroll
    for (int nb = 0; nb < 4; ++nb) { aq[mi][nb] = fz; ak[mi][nb] = fz; }
#pragma unroll
  for (int mt = 0; mt < 4; ++mt) { av[mt][0] = fz; av[mt][1] = fz; }

  bf16x8 wqb[2][2], wkb[2][2], wvb[2][2];  // [buf][mi] double-buffered weights
#define LOADW(buf, kk)                                                             \
  do {                                                                             \
    if (PREP) {                                                                    \
      const bf16_t* wb = wf + (size_t)(kk)*512 + (size_t)lane * 8;                 \
      _Pragma("unroll") for (int mi = 0; mi < 2; ++mi) {                           \
        wqb[buf][mi] = *(const bf16x8*)(wb + (size_t)(h * 2 + mi) * 4096);         \
        wkb[buf][mi] = *(const bf16x8*)(wb + (size_t)(16 + h * 2 + mi) * 4096);    \
        wvb[buf][mi] = *(const bf16x8*)(wb + (size_t)(32 + h * 2 + mi) * 4096);    \
      }                                                                            \
    } else {                                                                       \
      _Pragma("unroll") for (int mi = 0; mi < 2; ++mi) {                           \
        wqb[buf][mi] = cvt8(Wq + (h * 32 + mi * 16 + l16) * 256 + (kk)*32 + quad * 8); \
        wkb[buf][mi] = cvt8(Wk + (h * 32 + mi * 16 + l16) * 256 + (kk)*32 + quad * 8); \
        wvb[buf][mi] = cvt8(Wv + (h * 32 + mi * 16 + l16) * 256 + (kk)*32 + quad * 8); \
      }                                                                            \
    }                                                                              \
  } while (0)

  LOADW(0, 0);
#pragma unroll
  for (int kk = 0; kk < 8; ++kk) {
    const int cur = kk & 1;
    if (kk < 7) LOADW(cur ^ 1, kk + 1);  // next-step weights issued before MFMAs
    bf16x8 af[4];
    const bf16_t* xb = xsf + ((kk * 4 + quad) * 64 + l16) * 8;
#pragma unroll
    for (int tb = 0; tb < 4; ++tb) af[tb] = *(const bf16x8*)(xb + tb * 128);
#pragma unroll
    for (int mi = 0; mi < 2; ++mi)
#pragma unroll
      for (int tb = 0; tb < 4; ++tb) {
        aq[mi][tb] = mfma16(wqb[cur][mi], af[tb], aq[mi][tb]);
        ak[mi][tb] = mfma16(wkb[cur][mi], af[tb], ak[mi][tb]);
      }
#pragma unroll
    for (int mt = 0; mt < 4; ++mt)
#pragma unroll
      for (int nd = 0; nd < 2; ++nd)
        av[mt][nd] = mfma16(af[mt], wvb[cur][nd], av[mt][nd]);
  }
#undef LOADW

  // ---- Phase B: bias + cosine-normalize (lane-local + 2 shfl), pack to bf16 ----
  float bqv[2][4], bkv[2][4];
#pragma unroll
  for (int mi = 0; mi < 2; ++mi)
#pragma unroll
    for (int r = 0; r < 4; ++r) {
      bqv[mi][r] = bq[h * 32 + mi * 16 + quad * 4 + r];
      bkv[mi][r] = bk[h * 32 + mi * 16 + quad * 4 + r];
    }
  const float bv0 = bv[h * 32 + l16], bv1 = bv[h * 32 + 16 + l16];

  uint32_t qlo[2][4], qhi[2][4], klo[2][4], khi[2][4];
#pragma unroll
  for (int nb = 0; nb < 4; ++nb) {
    float qv[2][4], kv[2][4];
    float sq = 0.f, sk = 0.f;
#pragma unroll
    for (int mi = 0; mi < 2; ++mi)
#pragma unroll
      for (int r = 0; r < 4; ++r) {
        float q0 = aq[mi][nb][r] + bqv[mi][r];
        float k0 = ak[mi][nb][r] + bkv[mi][r];
        qv[mi][r] = q0; kv[mi][r] = k0;
        sq += q0 * q0; sk += k0 * k0;
      }
    sq += __shfl_xor(sq, 16); sq += __shfl_xor(sq, 32);
    sk += __shfl_xor(sk, 16); sk += __shfl_xor(sk, 32);
    const float rq = 1.f / fmaxf(sqrtf(sq), 1e-12f);
    const float rk = 1.f / fmaxf(sqrtf(sk), 1e-12f);
#pragma unroll
    for (int mi = 0; mi < 2; ++mi) {
      qlo[mi][nb] = pack2(qv[mi][0] * rq, qv[mi][1] * rq);
      qhi[mi][nb] = pack2(qv[mi][2] * rq, qv[mi][3] * rq);
      klo[mi][nb] = pack2(kv[mi][0] * rk, kv[mi][1] * rk);
      khi[mi][nb] = pack2(kv[mi][2] * rk, kv[mi][3] * rk);
    }
  }
  uint32_t vlo[4][2], vhi[4][2];
#pragma unroll
  for (int mt = 0; mt < 4; ++mt)
#pragma unroll
    for (int nd = 0; nd < 2; ++nd) {
      const float bvb = nd ? bv1 : bv0;
      vlo[mt][nd] = pack2(av[mt][nd][0] + bvb, av[mt][nd][1] + bvb);
      vhi[mt][nd] = pack2(av[mt][nd][2] + bvb, av[mt][nd][3] + bvb);
    }

  // ---- Phase C: S^T = kn @ qn^T, fragments built in-register ----
  bf16x8 kfr[4], qfr[4];
#pragma unroll
  for (int tb = 0; tb < 4; ++tb)
    kfr[tb] = quadshuf(klo[0][tb], khi[0][tb], klo[1][tb], khi[1][tb], sA, sB, miHi);
#pragma unroll
  for (int tb = 0; tb < 4; ++tb)
    qfr[tb] = quadshuf(qlo[0][tb], qhi[0][tb], qlo[1][tb], qhi[1][tb], sA, sB, miHi);
  f32x4 s[4][4];  // s[KB][NB]: lane holds S[query NB*16+l16][key KB*16+quad*4+r]
#pragma unroll
  for (int KB = 0; KB < 4; ++KB)
#pragma unroll
    for (int NB = 0; NB < 4; ++NB) s[KB][NB] = mfma16(kfr[KB], qfr[NB], fz);

  const float scale = __expf(fminf(ls[h], 4.6051702f));  // exp(min(ls, ln 100))

  // ---- scale + CPB bias + shifted-window mask ----
#pragma unroll
  for (int KB = 0; KB < 4; ++KB) {
    const int mrow = KB * 2 + (quad >> 1);
    const int mcol0 = (quad & 1) * 4;
#pragma unroll
    for (int NB = 0; NB < 4; ++NB) {
      const int base = ((NB * 2 + (l16 >> 3)) - mrow + 7) * 15 +
                       ((l16 & 7) - mcol0 + 7);
      const bool msk = (regn[NB] != regm[KB]);
#pragma unroll
      for (int r = 0; r < 4; ++r) {
        float v = s[KB][NB][r] * scale + btab[(base - r) * 8 + h];
        if (msk) v -= 100.f;
        s[KB][NB][r] = v;
      }
    }
  }

  // ---- Phase D: softmax over keys (lane-local 16 + 2 shfl per query col) ----
  uint32_t plo[4][4], phi[4][4];
#pragma unroll
  for (int NB = 0; NB < 4; ++NB) {
    float mx = s[0][NB][0];
#pragma unroll
    for (int KB = 0; KB < 4; ++KB)
#pragma unroll
      for (int r = 0; r < 4; ++r) mx = fmaxf(mx, s[KB][NB][r]);
    mx = fmaxf(mx, __shfl_xor(mx, 16));
    mx = fmaxf(mx, __shfl_xor(mx, 32));
    float sum = 0.f;
#pragma unroll
    for (int KB = 0; KB < 4; ++KB)
#pragma unroll
      for (int r = 0; r < 4; ++r) {
        float p = __expf(s[KB][NB][r] - mx);
        s[KB][NB][r] = p;
        sum += p;
      }
    sum += __shfl_xor(sum, 16); sum += __shfl_xor(sum, 32);
    const float inv = 1.f / sum;
#pragma unroll
    for (int KB = 0; KB < 4; ++KB) {
      plo[KB][NB] = pack2(s[KB][NB][0] * inv, s[KB][NB][1] * inv);
      phi[KB][NB] = pack2(s[KB][NB][2] * inv, s[KB][NB][3] * inv);
    }
  }

  // ---- Phase E: O^T = V^T @ P (fragments in-register, 2 K-steps of 32 keys) ----
  f32x4 oh[2][4];  // [dim-block][query-block]
#pragma unroll
  for (int DB = 0; DB < 2; ++DB)
#pragma unroll
    for (int NB = 0; NB < 4; ++NB) oh[DB][NB] = fz;
#pragma unroll
  for (int st = 0; st < 2; ++st) {
    bf16x8 vfr[2], pfr[4];
#pragma unroll
    for (int DB = 0; DB < 2; ++DB)
      vfr[DB] = quadshuf(vlo[2 * st][DB], vhi[2 * st][DB],
                         vlo[2 * st + 1][DB], vhi[2 * st + 1][DB], sA, sB, miHi);
#pragma unroll
    for (int NB = 0; NB < 4; ++NB)
      pfr[NB] = quadshuf(plo[2 * st][NB], phi[2 * st][NB],
                         plo[2 * st + 1][NB], phi[2 * st + 1][NB], sA, sB, miHi);
#pragma unroll
    for (int DB = 0; DB < 2; ++DB)
#pragma unroll
      for (int NB = 0; NB < 4; ++NB)
        oh[DB][NB] = mfma16(vfr[DB], pfr[NB], oh[DB][NB]);
  }

  // all waves past their Phase-A xsf reads here; overlay y frags on xsf.
  __syncthreads();
  // write O^T into y frags: channel f = h*32 + DB*16 + quad*4 + r, token nb*16+l16
#pragma unroll
  for (int DB = 0; DB < 2; ++DB)
#pragma unroll
    for (int nb = 0; nb < 4; ++nb)
#pragma unroll
      for (int r = 0; r < 4; ++r)
        xsf[(h * 4 + DB * 2 + (quad >> 1)) * 512 + (nb * 16 + l16) * 8 +
            ((quad & 1) << 2) + r] = (bf16_t)oh[DB][nb][r];
  __syncthreads();

  // ---- Phase F: out = y @ Wo^T + bo, software-pipelined Wo loads ----
  f32x4 a2[4][2];
#pragma unroll
  for (int mi = 0; mi < 4; ++mi) { a2[mi][0] = fz; a2[mi][1] = fz; }

  bf16x8 wob[2][2];  // [buf][ni]
#define LOADWO(buf, kk)                                                              \
  do {                                                                               \
    _Pragma("unroll") for (int ni = 0; ni < 2; ++ni) {                               \
      if (PREP)                                                                      \
        wob[buf][ni] = *(const bf16x8*)(                                             \
            wf + (size_t)(((48 + wave * 2 + ni) * 8 + (kk)) * 64 + lane) * 8);       \
      else                                                                           \
        wob[buf][ni] =                                                               \
            cvt8(Wo + (wave * 32 + ni * 16 + l16) * 256 + (kk)*32 + quad * 8);       \
    }                                                                                \
  } while (0)

  LOADWO(0, 0);
#pragma unroll
  for (int kk = 0; kk < 8; ++kk) {
    const int cur = kk & 1;
    if (kk < 7) LOADWO(cur ^ 1, kk + 1);
    bf16x8 af[4];
    const bf16_t* yb = xsf + ((kk * 4 + quad) * 64 + l16) * 8;
#pragma unroll
    for (int mi = 0; mi < 4; ++mi) af[mi] = *(const bf16x8*)(yb + mi * 128);
#pragma unroll
    for (int ni = 0; ni < 2; ++ni)
#pragma unroll
      for (int mi = 0; mi < 4; ++mi) a2[mi][ni] = mfma16(af[mi], wob[cur][ni], a2[mi][ni]);
  }
#undef LOADWO

  const float bor0 = bo[wave * 32 + l16], bor1 = bo[wave * 32 + 16 + l16];
#pragma unroll
  for (int mi = 0; mi < 4; ++mi)
#pragma unroll
    for (int r = 0; r < 4; ++r) {
      int row = mi * 16 + quad * 4 + r;
      int gh = (wh * 8 + (row >> 3) + 4) & 63;
      int gw = (ww * 8 + (row & 7) + 4) & 63;
      float* op = out + (size_t)((bb * 64 + gh) * 64 + gw) * 256 + wave * 32 + l16;
      op[0]  = clampv(a2[mi][0][r] + bor0);
      op[16] = clampv(a2[mi][1][r] + bor1);
    }
}

extern "C" void kernel_launch(void* const* d_in, const int* in_sizes, int n_in,
                              void* d_out, int out_size, void* d_ws, size_t ws_size,
                              hipStream_t stream) {
  const float* x  = (const float*)d_in[0];
  const float* Wq = (const float*)d_in[1];
  const float* bq = (const float*)d_in[2];
  const float* Wk = (const float*)d_in[3];
  const float* bk = (const float*)d_in[4];
  const float* Wv = (const float*)d_in[5];
  const float* bv = (const float*)d_in[6];
  const float* Wo = (const float*)d_in[7];
  const float* bo = (const float*)d_in[8];
  const float* ls = (const float*)d_in[9];
  const float* w1 = (const float*)d_in[10];
  const float* b1 = (const float*)d_in[11];
  const float* w2 = (const float*)d_in[12];

  float* tab = (float*)d_ws;                           // 1800 floats (7.2 KB)
  bf16_t* wfrag = (bf16_t*)((char*)d_ws + 7680);       // 512 KB fragment-major weights
  const bool prep = ws_size >= (size_t)(7680 + 524288);  // constant across calls

  hipLaunchKernelGGL(prep_all, dim3(353), dim3(256), 0, stream,
                     Wq, Wk, Wv, Wo, w1, b1, w2, wfrag, tab, prep ? 1 : 0);
  if (prep) {
    hipLaunchKernelGGL((swin_fused<true>), dim3(2048), dim3(512), 0, stream,
                       x, Wq, bq, Wk, bk, Wv, bv, Wo, bo, ls, tab, wfrag, (float*)d_out);
  } else {
    hipLaunchKernelGGL((swin_fused<false>), dim3(2048), dim3(512), 0, stream,
                       x, Wq, bq, Wk, bk, Wv, bv, Wo, bo, ls, tab, wfrag, (float*)d_out);
  }
}